// Round 4
// baseline (4578.143 us; speedup 1.0000x reference)
//
#include <hip/hip_runtime.h>
#include <math.h>

#define N_ 32
#define T_ 365
#define B_ 128

__device__ __forceinline__ float gelu_f(float x) {
    return 0.5f * x * (1.0f + erff(x * 0.70710678118654752440f));
}
__device__ __forceinline__ float sigmoid_f(float x) {
    return 1.0f / (1.0f + expf(-x));
}

union F4 { float4 v; float f[4]; };

// ---------------- K0: adjacency normalization (once, tiny) ----------------
__global__ void __launch_bounds__(128) prep_adj(const float* __restrict__ adj,
                                                float* __restrict__ adjn_rm,
                                                float* __restrict__ adjnT) {
    __shared__ float d[128];
    const int u = threadIdx.x;
    float s = 0.f;
    #pragma unroll 8
    for (int v4 = 0; v4 < 32; ++v4) {
        F4 a4; a4.v = *reinterpret_cast<const float4*>(adj + u * 128 + v4 * 4);
        s += (a4.f[0] + a4.f[1]) + (a4.f[2] + a4.f[3]);
    }
    s = fmaxf(s, 1.0f);
    d[u] = 1.0f / sqrtf(s);
    __syncthreads();
    const float du = d[u];
    for (int v = 0; v < 128; ++v) {
        const float val = du * adj[u * 128 + v] * d[v];
        adjn_rm[u * 128 + v] = val;   // adjn[u][v]
        adjnT[v * 128 + u]  = val;    // adjn[u][v] stored transposed
    }
}

// ---------------- K1: fused GCN pipeline per (n,t) tile ----------------
// xg[n*T+t][j] = h2 @ Wih^T + (bih + bhh)
// h2 = gelu( (adjn[u*,:] @ gelu(adjn @ ((gelu(In@pd_W+b)) @ g1_W) + g1_b)) @ g2_W + g2_b )
// LDS 36.6KB -> 4 blocks/CU (16 waves). Inputs/weights read straight from
// global (L1-hot: weights+adjn reused by ~46 sequential tiles per CU).
__global__ void __launch_bounds__(256, 4) gcn_fused(
    const float* __restrict__ input,
    const float* __restrict__ adjn_rm,
    const float* __restrict__ adjnT,
    const int*   __restrict__ basin_idx,
    const float* __restrict__ pd_W, const float* __restrict__ pd_b,
    const float* __restrict__ g1_W, const float* __restrict__ g1_b,
    const float* __restrict__ g2_W, const float* __restrict__ g2_b,
    const float* __restrict__ l_Wih, const float* __restrict__ l_bih,
    const float* __restrict__ l_bhh,
    float* __restrict__ xg_out)
{
    __shared__ __align__(16) float sA[32][132];     // transposed buf: X1T -> H1T (16.9KB)
    __shared__ __align__(16) float sY[128][36];     // row-major buf: Y (18.4KB)
    __shared__ float h2s[32];
    __shared__ float qs[32];
    __shared__ float part[32][8];

    const int tid = threadIdx.x;
    const int bid = blockIdx.x;                      // = n*T + t
    const int n = bid / T_;
    const float* inp = input + (size_t)bid * (B_ * 48);

    const int rb = tid >> 3, cb = tid & 7;
    const int r0 = rb << 2, c0 = cb << 2;            // 32 row-blocks x 8 col-blocks
    float acc[4][4];

    // ---- M1: X1 = gelu(In @ pd_W + pd_b). In read DIRECTLY from global
    // (dense cols 0..31 of the 48-float rows); pd_W from global (L1-hot).
    #pragma unroll
    for (int a = 0; a < 4; ++a)
        #pragma unroll
        for (int b = 0; b < 4; ++b) acc[a][b] = 0.f;
    #pragma unroll
    for (int k4 = 0; k4 < 8; ++k4) {
        F4 w0, w1, w2, w3;
        w0.v = *reinterpret_cast<const float4*>(pd_W + (k4 * 4 + 0) * 32 + c0);
        w1.v = *reinterpret_cast<const float4*>(pd_W + (k4 * 4 + 1) * 32 + c0);
        w2.v = *reinterpret_cast<const float4*>(pd_W + (k4 * 4 + 2) * 32 + c0);
        w3.v = *reinterpret_cast<const float4*>(pd_W + (k4 * 4 + 3) * 32 + c0);
        #pragma unroll
        for (int a = 0; a < 4; ++a) {
            F4 r; r.v = *reinterpret_cast<const float4*>(inp + (r0 + a) * 48 + k4 * 4);
            #pragma unroll
            for (int b = 0; b < 4; ++b)
                acc[a][b] += r.f[0] * w0.f[b] + r.f[1] * w1.f[b]
                           + r.f[2] * w2.f[b] + r.f[3] * w3.f[b];
        }
    }
    {
        F4 bv; bv.v = *reinterpret_cast<const float4*>(pd_b + c0);
        #pragma unroll
        for (int jc = 0; jc < 4; ++jc) {
            F4 o;
            #pragma unroll
            for (int jr = 0; jr < 4; ++jr) o.f[jr] = gelu_f(acc[jr][jc] + bv.f[jc]);
            *reinterpret_cast<float4*>(&sA[c0 + jc][r0]) = o.v;   // X1T
        }
    }
    __syncthreads();

    // ---- M2: Y = X1 @ g1_W (no bias/act) -> sY (row-major); g1_W from global
    #pragma unroll
    for (int a = 0; a < 4; ++a)
        #pragma unroll
        for (int b = 0; b < 4; ++b) acc[a][b] = 0.f;
    #pragma unroll 8
    for (int k = 0; k < 32; ++k) {
        F4 av; av.v = *reinterpret_cast<const float4*>(&sA[k][r0]);
        F4 wv; wv.v = *reinterpret_cast<const float4*>(g1_W + k * 32 + c0);
        #pragma unroll
        for (int a = 0; a < 4; ++a)
            #pragma unroll
            for (int b = 0; b < 4; ++b) acc[a][b] += av.f[a] * wv.f[b];
    }
    #pragma unroll
    for (int jr = 0; jr < 4; ++jr) {
        F4 o;
        #pragma unroll
        for (int jc = 0; jc < 4; ++jc) o.f[jc] = acc[jr][jc];
        *reinterpret_cast<float4*>(&sY[r0 + jr][c0]) = o.v;
    }
    __syncthreads();

    // ---- M3: H1 = gelu(adjn @ Y + g1_b) -> sA (X1T dead). adjnT L2-hot stream.
    #pragma unroll
    for (int a = 0; a < 4; ++a)
        #pragma unroll
        for (int b = 0; b < 4; ++b) acc[a][b] = 0.f;
    #pragma unroll 8
    for (int v = 0; v < 128; ++v) {
        F4 av; av.v = *reinterpret_cast<const float4*>(adjnT + v * 128 + r0); // adjn[u0..3][v]
        F4 yv; yv.v = *reinterpret_cast<const float4*>(&sY[v][c0]);
        #pragma unroll
        for (int a = 0; a < 4; ++a)
            #pragma unroll
            for (int b = 0; b < 4; ++b) acc[a][b] += av.f[a] * yv.f[b];
    }
    {
        F4 bv; bv.v = *reinterpret_cast<const float4*>(g1_b + c0);
        #pragma unroll
        for (int jh = 0; jh < 4; ++jh) {
            F4 o;
            #pragma unroll
            for (int ju = 0; ju < 4; ++ju) o.f[ju] = gelu_f(acc[ju][jh] + bv.f[jh]);
            *reinterpret_cast<float4*>(&sA[c0 + jh][r0]) = o.v;   // H1T
        }
    }
    __syncthreads();

    // ---- M4': q = adjn[u*,:] @ H1   (basin row only; reads H1T in sA)
    const int ustar = basin_idx[n];
    {
        const int hp = tid >> 3, uc = tid & 7;
        const float* arow = adjn_rm + (size_t)ustar * 128 + uc * 16;
        const float* hrow = &sA[hp][uc * 16];
        float p = 0.f;
        #pragma unroll
        for (int u4 = 0; u4 < 4; ++u4) {
            F4 a4; a4.v = *reinterpret_cast<const float4*>(arow + 4 * u4);
            F4 h4; h4.v = *reinterpret_cast<const float4*>(hrow + 4 * u4);
            p += a4.f[0] * h4.f[0] + a4.f[1] * h4.f[1]
               + a4.f[2] * h4.f[2] + a4.f[3] * h4.f[3];
        }
        part[hp][uc] = p;
    }
    __syncthreads();
    if (tid < 32) {
        float s = 0.f;
        #pragma unroll
        for (int uc = 0; uc < 8; ++uc) s += part[tid][uc];
        qs[tid] = s;
    }
    __syncthreads();

    // ---- M5': h2 = gelu(q @ g2_W + g2_b)  (g2_W from global, coalesced over tid)
    if (tid < 32) {
        float a = g2_b[tid];
        #pragma unroll 8
        for (int k = 0; k < 32; ++k) a += qs[k] * g2_W[k * 32 + tid];
        h2s[tid] = gelu_f(a);
    }
    __syncthreads();

    // ---- xg = h2 @ Wih^T + (bih + bhh)
    if (tid < 128) {
        float a = l_bih[tid] + l_bhh[tid];
        const float* wr = l_Wih + tid * 32;
        #pragma unroll
        for (int h = 0; h < 32; h += 4) {
            F4 w4; w4.v = *reinterpret_cast<const float4*>(wr + h);
            a += h2s[h] * w4.f[0] + h2s[h + 1] * w4.f[1]
               + h2s[h + 2] * w4.f[2] + h2s[h + 3] * w4.f[3];
        }
        xg_out[(size_t)bid * 128 + tid] = a;
    }
}

// ---------------- K3: LSTM, 32 independent rows, 1 wave each ----------------
// All-register: h broadcast via __shfl (no LDS, no barriers).
// Lane l<32: gates i(s0),g(s1) for h-index l; lane l+32: f(s0),o(s1).
__global__ void __launch_bounds__(64) lstm_k(const float* __restrict__ xg,
                                             const float* __restrict__ Whh,
                                             float* __restrict__ h_last) {
    const int n = blockIdx.x, lane = threadIdx.x;
    float w0[32], w1[32];
    #pragma unroll
    for (int k = 0; k < 32; k += 4) {
        *reinterpret_cast<float4*>(&w0[k]) = *reinterpret_cast<const float4*>(Whh + lane * 32 + k);
        *reinterpret_cast<float4*>(&w1[k]) = *reinterpret_cast<const float4*>(Whh + (lane + 64) * 32 + k);
    }
    float c = 0.f;
    float hv = 0.f;                 // h[lane & 31], duplicated in both wave halves
    const float* xgn = xg + (size_t)n * T_ * 128;
    float a0 = xgn[lane], a1 = xgn[lane + 64];
    for (int t = 0; t < T_; ++t) {
        float na0 = 0.f, na1 = 0.f;
        if (t < T_ - 1) {
            na0 = xgn[(t + 1) * 128 + lane];
            na1 = xgn[(t + 1) * 128 + lane + 64];
        }
        float p0[4] = {0.f, 0.f, 0.f, 0.f};
        float p1[4] = {0.f, 0.f, 0.f, 0.f};
        #pragma unroll
        for (int k = 0; k < 32; ++k) {
            const float hk = __shfl(hv, k);      // lane k (<32) holds h_k
            p0[k & 3] = fmaf(w0[k], hk, p0[k & 3]);
            p1[k & 3] = fmaf(w1[k], hk, p1[k & 3]);
        }
        const float s0 = a0 + ((p0[0] + p0[1]) + (p0[2] + p0[3]));
        const float s1 = a1 + ((p1[0] + p1[1]) + (p1[2] + p1[3]));
        const float b0 = __shfl_xor(s0, 32);
        const float b1 = __shfl_xor(s1, 32);
        const bool lo = lane < 32;
        const float iv = lo ? s0 : b0, fv = lo ? b0 : s0;
        const float gv = lo ? s1 : b1, ov = lo ? b1 : s1;
        c = sigmoid_f(fv) * c + sigmoid_f(iv) * tanhf(gv);
        hv = sigmoid_f(ov) * tanhf(c);           // identical in lanes l and l+32
        a0 = na0; a1 = na1;
    }
    if (lane < 32) h_last[n * 32 + lane] = hv;
}

// ---------------- K4: s-path, gates, batchnorm, readout (single block) ----------------
__global__ void __launch_bounds__(256) final_k(
    const float* __restrict__ input, const int* __restrict__ basin_idx,
    const float* __restrict__ h_last,
    const float* __restrict__ ps_W, const float* __restrict__ ps_b,
    const float* __restrict__ sp_W1, const float* __restrict__ sp_b1,
    const float* __restrict__ sp_W2, const float* __restrict__ sp_b2,
    const float* __restrict__ gd_W1, const float* __restrict__ gd_b1,
    const float* __restrict__ gd_W2, const float* __restrict__ gd_b2,
    const float* __restrict__ gs_W1, const float* __restrict__ gs_b1,
    const float* __restrict__ gs_W2, const float* __restrict__ gs_b2,
    const float* __restrict__ bn_g, const float* __restrict__ bn_b,
    const float* __restrict__ r_W, const float* __restrict__ r_b,
    float* __restrict__ out)
{
    __shared__ float ss[32][16];
    __shared__ float s1[32][32];
    __shared__ float s2[32][32];
    __shared__ float xs[32][32];
    __shared__ float t1[32][64];
    __shared__ float wd[32][32], wsg[32][32];
    __shared__ float hc[32][64];
    __shared__ float mu[64], ivr[64];
    const int tid = threadIdx.x;

    for (int i = tid; i < 512; i += 256) {
        const int nn = i >> 4, k = i & 15;
        ss[nn][k] = input[((size_t)(nn * T_ + (T_ - 1)) * B_ + basin_idx[nn]) * 48 + 32 + k];
    }
    for (int i = tid; i < 1024; i += 256) xs[i >> 5][i & 31] = h_last[i];
    __syncthreads();

    // s1 = gelu(ss @ ps_W + ps_b)
    for (int i = tid; i < 1024; i += 256) {
        const int nn = i >> 5, p = i & 31;
        float a = ps_b[p];
        for (int k = 0; k < 16; ++k) a += ss[nn][k] * ps_W[k * 32 + p];
        s1[nn][p] = gelu_f(a);
    }
    __syncthreads();
    // s2 = gelu(s1 @ sp_W1 + sp_b1)
    for (int i = tid; i < 1024; i += 256) {
        const int nn = i >> 5, p = i & 31;
        float a = sp_b1[p];
        for (int k = 0; k < 32; ++k) a += s1[nn][k] * sp_W1[k * 32 + p];
        s2[nn][p] = gelu_f(a);
    }
    __syncthreads();
    // s3 = gelu(s2 @ sp_W2 + sp_b2) -> back into s1
    for (int i = tid; i < 1024; i += 256) {
        const int nn = i >> 5, p = i & 31;
        float a = sp_b2[p];
        for (int k = 0; k < 32; ++k) a += s2[nn][k] * sp_W2[k * 32 + p];
        s1[nn][p] = gelu_f(a);
    }
    __syncthreads();

    // t1 = gelu(xs @ gd_W1 + gd_b1)
    for (int i = tid; i < 2048; i += 256) {
        const int nn = i >> 6, e = i & 63;
        float a = gd_b1[e];
        for (int k = 0; k < 32; ++k) a += xs[nn][k] * gd_W1[k * 64 + e];
        t1[nn][e] = gelu_f(a);
    }
    __syncthreads();
    // wd = sigmoid(t1 @ gd_W2 + gd_b2)
    for (int i = tid; i < 1024; i += 256) {
        const int nn = i >> 5, p = i & 31;
        float a = gd_b2[p];
        for (int k = 0; k < 64; ++k) a += t1[nn][k] * gd_W2[k * 32 + p];
        wd[nn][p] = sigmoid_f(a);
    }
    __syncthreads();
    // t1 = gelu(xs @ gs_W1 + gs_b1)
    for (int i = tid; i < 2048; i += 256) {
        const int nn = i >> 6, e = i & 63;
        float a = gs_b1[e];
        for (int k = 0; k < 32; ++k) a += xs[nn][k] * gs_W1[k * 64 + e];
        t1[nn][e] = gelu_f(a);
    }
    __syncthreads();
    // wsg = sigmoid(t1 @ gs_W2 + gs_b2)
    for (int i = tid; i < 1024; i += 256) {
        const int nn = i >> 5, p = i & 31;
        float a = gs_b2[p];
        for (int k = 0; k < 64; ++k) a += t1[nn][k] * gs_W2[k * 32 + p];
        wsg[nn][p] = sigmoid_f(a);
    }
    __syncthreads();

    // hcat
    for (int i = tid; i < 2048; i += 256) {
        const int nn = i >> 6, cc = i & 63;
        hc[nn][cc] = (cc < 32) ? xs[nn][cc] * wd[nn][cc]
                               : s1[nn][cc - 32] * wsg[nn][cc - 32];
    }
    __syncthreads();

    // batchnorm stats over the 32 rows (biased var, two-pass like reference)
    if (tid < 64) {
        float m = 0.f;
        for (int nn = 0; nn < 32; ++nn) m += hc[nn][tid];
        m *= (1.0f / 32.0f);
        float v = 0.f;
        for (int nn = 0; nn < 32; ++nn) { const float d = hc[nn][tid] - m; v += d * d; }
        v *= (1.0f / 32.0f);
        mu[tid] = m;
        ivr[tid] = 1.0f / sqrtf(v + 1e-5f);
    }
    __syncthreads();

    if (tid < 32) {
        float a = r_b[0];
        for (int cc = 0; cc < 64; ++cc) {
            const float hn = (hc[tid][cc] - mu[cc]) * ivr[cc] * bn_g[cc] + bn_b[cc];
            a += hn * r_W[cc];
        }
        out[tid] = a;
    }
}

// ---------------- launcher ----------------
extern "C" void kernel_launch(void* const* d_in, const int* in_sizes, int n_in,
                              void* d_out, int out_size, void* d_ws, size_t ws_size,
                              hipStream_t stream) {
    const float* input  = (const float*)d_in[0];
    const float* adj    = (const float*)d_in[1];
    const int*   basin  = (const int*)  d_in[2];
    const float* pd_W   = (const float*)d_in[3];
    const float* pd_b   = (const float*)d_in[4];
    const float* ps_W   = (const float*)d_in[5];
    const float* ps_b   = (const float*)d_in[6];
    const float* g1_W   = (const float*)d_in[7];
    const float* g1_b   = (const float*)d_in[8];
    const float* g2_W   = (const float*)d_in[9];
    const float* g2_b   = (const float*)d_in[10];
    const float* l_Wih  = (const float*)d_in[11];
    const float* l_Whh  = (const float*)d_in[12];
    const float* l_bih  = (const float*)d_in[13];
    const float* l_bhh  = (const float*)d_in[14];
    const float* gd_W1  = (const float*)d_in[15];
    const float* gd_b1  = (const float*)d_in[16];
    const float* gd_W2  = (const float*)d_in[17];
    const float* gd_b2  = (const float*)d_in[18];
    const float* gs_W1  = (const float*)d_in[19];
    const float* gs_b1  = (const float*)d_in[20];
    const float* gs_W2  = (const float*)d_in[21];
    const float* gs_b2  = (const float*)d_in[22];
    const float* sp_W1  = (const float*)d_in[23];
    const float* sp_b1  = (const float*)d_in[24];
    const float* sp_W2  = (const float*)d_in[25];
    const float* sp_b2  = (const float*)d_in[26];
    const float* bn_g   = (const float*)d_in[27];
    const float* bn_b   = (const float*)d_in[28];
    const float* r_W    = (const float*)d_in[29];
    const float* r_b    = (const float*)d_in[30];
    float* out = (float*)d_out;

    float* ws       = (float*)d_ws;
    float* adjn_rm  = ws;                                // 16384 floats
    float* adjnT    = ws + 16384;                        // 16384 floats
    float* xg       = ws + 32768;                        // N*T*128 = 1,495,040 floats
    float* h_last   = xg + (size_t)N_ * T_ * 128;        // 1024 floats

    hipLaunchKernelGGL(prep_adj, dim3(1), dim3(128), 0, stream, adj, adjn_rm, adjnT);
    hipLaunchKernelGGL(gcn_fused, dim3(N_ * T_), dim3(256), 0, stream,
                       input, adjn_rm, adjnT, basin,
                       pd_W, pd_b, g1_W, g1_b, g2_W, g2_b,
                       l_Wih, l_bih, l_bhh, xg);
    hipLaunchKernelGGL(lstm_k, dim3(N_), dim3(64), 0, stream, xg, l_Whh, h_last);
    hipLaunchKernelGGL(final_k, dim3(1), dim3(256), 0, stream,
                       input, basin, h_last,
                       ps_W, ps_b, sp_W1, sp_b1, sp_W2, sp_b2,
                       gd_W1, gd_b1, gd_W2, gd_b2,
                       gs_W1, gs_b1, gs_W2, gs_b2,
                       bn_g, bn_b, r_W, r_b, out);
}

// Round 6
// 898.552 us; speedup vs baseline: 5.0950x; 5.0950x over previous
//
#include <hip/hip_runtime.h>
#include <math.h>

#define N_ 32
#define T_ 365
#define B_ 128

__device__ __forceinline__ float gelu_f(float x) {
    return 0.5f * x * (1.0f + erff(x * 0.70710678118654752440f));
}
__device__ __forceinline__ float sigmoid_f(float x) {
    return 1.0f / (1.0f + expf(-x));
}

union F4 { float4 v; float f[4]; };

// ---------------- K0: adjacency normalization (once, tiny) ----------------
__global__ void __launch_bounds__(128) prep_adj(const float* __restrict__ adj,
                                                float* __restrict__ adjn_rm,
                                                float* __restrict__ adjnT) {
    __shared__ float d[128];
    const int u = threadIdx.x;
    float s = 0.f;
    #pragma unroll 8
    for (int v4 = 0; v4 < 32; ++v4) {
        F4 a4; a4.v = *reinterpret_cast<const float4*>(adj + u * 128 + v4 * 4);
        s += (a4.f[0] + a4.f[1]) + (a4.f[2] + a4.f[3]);
    }
    s = fmaxf(s, 1.0f);
    d[u] = 1.0f / sqrtf(s);
    __syncthreads();
    const float du = d[u];
    for (int v = 0; v < 128; ++v) {
        const float val = du * adj[u * 128 + v] * d[v];
        adjn_rm[u * 128 + v] = val;   // adjn[u][v]
        adjnT[v * 128 + u]  = val;    // adjn[u][v] stored transposed
    }
}

// ---------------- K1: fused GCN pipeline per (n,t) tile ----------------
// xg[n*T+t][j] = h2 @ Wih^T + (bih + bhh)
// Input tile STAGED in LDS (read once, coalesced — round-4 regression proved
// un-staged reads explode HBM 140MB->12GB). Weights from global: 12KB shared
// by all blocks -> L1/L2-hot. LDS ~36.6KB -> 4 blocks/CU (16 waves).
__global__ void __launch_bounds__(256, 4) gcn_fused(
    const float* __restrict__ input,
    const float* __restrict__ adjn_rm,
    const float* __restrict__ adjnT,
    const int*   __restrict__ basin_idx,
    const float* __restrict__ pd_W, const float* __restrict__ pd_b,
    const float* __restrict__ g1_W, const float* __restrict__ g1_b,
    const float* __restrict__ g2_W, const float* __restrict__ g2_b,
    const float* __restrict__ l_Wih, const float* __restrict__ l_bih,
    const float* __restrict__ l_bhh,
    float* __restrict__ xg_out)
{
    __shared__ __align__(16) float sA[32][132];     // transposed buf: InT -> X1T -> H1T
    __shared__ __align__(16) float sY[128][36];     // row-major buf: Y
    __shared__ float h2s[32];
    __shared__ float qs[32];
    __shared__ float part[32][8];

    const int tid = threadIdx.x;
    const int bid = blockIdx.x;                      // = n*T + t
    const int n = bid / T_;
    const float* inp = input + (size_t)bid * (B_ * 48);

    // stage dense input transposed: sA[c][v] = input[n,t,v,c], c<32 (read ONCE, coalesced)
    for (int c = tid; c < 1024; c += 256) {
        const int v = c >> 3, c4 = (c & 7) << 2;
        F4 dv; dv.v = *reinterpret_cast<const float4*>(inp + v * 48 + c4);
        sA[c4 + 0][v] = dv.f[0]; sA[c4 + 1][v] = dv.f[1];
        sA[c4 + 2][v] = dv.f[2]; sA[c4 + 3][v] = dv.f[3];
    }
    __syncthreads();

    const int rb = tid >> 3, cb = tid & 7;
    const int r0 = rb << 2, c0 = cb << 2;            // 32 row-blocks x 8 col-blocks
    float acc[4][4];

    // ---- M1: X1 = gelu(In @ pd_W + pd_b): compute from sA(InT), weights global
    // (L1-hot), then write X1T back IN PLACE (barrier separates reads/writes).
    #pragma unroll
    for (int a = 0; a < 4; ++a)
        #pragma unroll
        for (int b = 0; b < 4; ++b) acc[a][b] = 0.f;
    #pragma unroll 8
    for (int k = 0; k < 32; ++k) {
        F4 av; av.v = *reinterpret_cast<const float4*>(&sA[k][r0]);
        F4 wv; wv.v = *reinterpret_cast<const float4*>(pd_W + k * 32 + c0);
        #pragma unroll
        for (int a = 0; a < 4; ++a)
            #pragma unroll
            for (int b = 0; b < 4; ++b) acc[a][b] += av.f[a] * wv.f[b];
    }
    __syncthreads();   // all InT reads done before overwrite
    {
        F4 bv; bv.v = *reinterpret_cast<const float4*>(pd_b + c0);
        #pragma unroll
        for (int jc = 0; jc < 4; ++jc) {
            F4 o;
            #pragma unroll
            for (int jr = 0; jr < 4; ++jr) o.f[jr] = gelu_f(acc[jr][jc] + bv.f[jc]);
            *reinterpret_cast<float4*>(&sA[c0 + jc][r0]) = o.v;   // X1T
        }
    }
    __syncthreads();

    // ---- M2: Y = X1 @ g1_W (no bias/act) -> sY (row-major); g1_W global (L1-hot)
    #pragma unroll
    for (int a = 0; a < 4; ++a)
        #pragma unroll
        for (int b = 0; b < 4; ++b) acc[a][b] = 0.f;
    #pragma unroll 8
    for (int k = 0; k < 32; ++k) {
        F4 av; av.v = *reinterpret_cast<const float4*>(&sA[k][r0]);
        F4 wv; wv.v = *reinterpret_cast<const float4*>(g1_W + k * 32 + c0);
        #pragma unroll
        for (int a = 0; a < 4; ++a)
            #pragma unroll
            for (int b = 0; b < 4; ++b) acc[a][b] += av.f[a] * wv.f[b];
    }
    #pragma unroll
    for (int jr = 0; jr < 4; ++jr) {
        F4 o;
        #pragma unroll
        for (int jc = 0; jc < 4; ++jc) o.f[jc] = acc[jr][jc];
        *reinterpret_cast<float4*>(&sY[r0 + jr][c0]) = o.v;
    }
    __syncthreads();

    // ---- M3: H1 = gelu(adjn @ Y + g1_b) -> sA (X1T dead). adjnT is 64KB,
    // shared by every block -> L1/L2-hot stream (proven OK in round 3).
    #pragma unroll
    for (int a = 0; a < 4; ++a)
        #pragma unroll
        for (int b = 0; b < 4; ++b) acc[a][b] = 0.f;
    #pragma unroll 8
    for (int v = 0; v < 128; ++v) {
        F4 av; av.v = *reinterpret_cast<const float4*>(adjnT + v * 128 + r0); // adjn[u0..3][v]
        F4 yv; yv.v = *reinterpret_cast<const float4*>(&sY[v][c0]);
        #pragma unroll
        for (int a = 0; a < 4; ++a)
            #pragma unroll
            for (int b = 0; b < 4; ++b) acc[a][b] += av.f[a] * yv.f[b];
    }
    {
        F4 bv; bv.v = *reinterpret_cast<const float4*>(g1_b + c0);
        #pragma unroll
        for (int jh = 0; jh < 4; ++jh) {
            F4 o;
            #pragma unroll
            for (int ju = 0; ju < 4; ++ju) o.f[ju] = gelu_f(acc[ju][jh] + bv.f[jh]);
            *reinterpret_cast<float4*>(&sA[c0 + jh][r0]) = o.v;   // H1T
        }
    }
    __syncthreads();

    // ---- M4': q = adjn[u*,:] @ H1   (basin row only; reads H1T in sA)
    const int ustar = basin_idx[n];
    {
        const int hp = tid >> 3, uc = tid & 7;
        const float* arow = adjn_rm + (size_t)ustar * 128 + uc * 16;
        const float* hrow = &sA[hp][uc * 16];
        float p = 0.f;
        #pragma unroll
        for (int u4 = 0; u4 < 4; ++u4) {
            F4 a4; a4.v = *reinterpret_cast<const float4*>(arow + 4 * u4);
            F4 h4; h4.v = *reinterpret_cast<const float4*>(hrow + 4 * u4);
            p += a4.f[0] * h4.f[0] + a4.f[1] * h4.f[1]
               + a4.f[2] * h4.f[2] + a4.f[3] * h4.f[3];
        }
        part[hp][uc] = p;
    }
    __syncthreads();
    if (tid < 32) {
        float s = 0.f;
        #pragma unroll
        for (int uc = 0; uc < 8; ++uc) s += part[tid][uc];
        qs[tid] = s;
    }
    __syncthreads();

    // ---- M5': h2 = gelu(q @ g2_W + g2_b)  (g2_W global, coalesced over tid)
    if (tid < 32) {
        float a = g2_b[tid];
        #pragma unroll 8
        for (int k = 0; k < 32; ++k) a += qs[k] * g2_W[k * 32 + tid];
        h2s[tid] = gelu_f(a);
    }
    __syncthreads();

    // ---- xg = h2 @ Wih^T + (bih + bhh)
    if (tid < 128) {
        float a = l_bih[tid] + l_bhh[tid];
        const float* wr = l_Wih + tid * 32;
        #pragma unroll
        for (int h = 0; h < 32; h += 4) {
            F4 w4; w4.v = *reinterpret_cast<const float4*>(wr + h);
            a += h2s[h] * w4.f[0] + h2s[h + 1] * w4.f[1]
               + h2s[h + 2] * w4.f[2] + h2s[h + 3] * w4.f[3];
        }
        xg_out[(size_t)bid * 128 + tid] = a;
    }
}

// ---------------- K3: LSTM, 32 independent rows, 1 wave each ----------------
// h-broadcast via v_readlane (pure VALU, no LDS/shfl latency in the k-loop).
// Lane l<32: rows l (i) and l+64 (g); lane l+32: rows f,o counterparts.
__global__ void __launch_bounds__(64) lstm_k(const float* __restrict__ xg,
                                             const float* __restrict__ Whh,
                                             float* __restrict__ h_last) {
    const int n = blockIdx.x, lane = threadIdx.x;
    float w0[32], w1[32];
    #pragma unroll
    for (int k = 0; k < 32; k += 4) {
        *reinterpret_cast<float4*>(&w0[k]) = *reinterpret_cast<const float4*>(Whh + lane * 32 + k);
        *reinterpret_cast<float4*>(&w1[k]) = *reinterpret_cast<const float4*>(Whh + (lane + 64) * 32 + k);
    }
    float c = 0.f;
    float hv = 0.f;                 // h[lane & 31], duplicated in both wave halves
    const float* xgn = xg + (size_t)n * T_ * 128;
    float a0 = xgn[lane], a1 = xgn[lane + 64];
    for (int t = 0; t < T_; ++t) {
        float na0 = 0.f, na1 = 0.f;
        if (t < T_ - 1) {
            na0 = xgn[(t + 1) * 128 + lane];
            na1 = xgn[(t + 1) * 128 + lane + 64];
        }
        float p0[4] = {0.f, 0.f, 0.f, 0.f};
        float p1[4] = {0.f, 0.f, 0.f, 0.f};
        #pragma unroll
        for (int k = 0; k < 32; ++k) {
            // h_k lives in lane k (<32); readlane -> SGPR broadcast, no memory op
            const float hk = __uint_as_float(
                __builtin_amdgcn_readlane(__float_as_uint(hv), k));
            p0[k & 3] = fmaf(w0[k], hk, p0[k & 3]);
            p1[k & 3] = fmaf(w1[k], hk, p1[k & 3]);
        }
        const float s0 = a0 + ((p0[0] + p0[1]) + (p0[2] + p0[3]));
        const float s1 = a1 + ((p1[0] + p1[1]) + (p1[2] + p1[3]));
        const float b0 = __shfl_xor(s0, 32);
        const float b1 = __shfl_xor(s1, 32);
        const bool lo = lane < 32;
        const float iv = lo ? s0 : b0, fv = lo ? b0 : s0;
        const float gv = lo ? s1 : b1, ov = lo ? b1 : s1;
        c = sigmoid_f(fv) * c + sigmoid_f(iv) * tanhf(gv);
        hv = sigmoid_f(ov) * tanhf(c);           // identical in lanes l and l+32
        a0 = na0; a1 = na1;
    }
    if (lane < 32) h_last[n * 32 + lane] = hv;
}

// ---------------- K4: s-path, gates, batchnorm, readout (single block) ----------------
__global__ void __launch_bounds__(256) final_k(
    const float* __restrict__ input, const int* __restrict__ basin_idx,
    const float* __restrict__ h_last,
    const float* __restrict__ ps_W, const float* __restrict__ ps_b,
    const float* __restrict__ sp_W1, const float* __restrict__ sp_b1,
    const float* __restrict__ sp_W2, const float* __restrict__ sp_b2,
    const float* __restrict__ gd_W1, const float* __restrict__ gd_b1,
    const float* __restrict__ gd_W2, const float* __restrict__ gd_b2,
    const float* __restrict__ gs_W1, const float* __restrict__ gs_b1,
    const float* __restrict__ gs_W2, const float* __restrict__ gs_b2,
    const float* __restrict__ bn_g, const float* __restrict__ bn_b,
    const float* __restrict__ r_W, const float* __restrict__ r_b,
    float* __restrict__ out)
{
    __shared__ float ss[32][16];
    __shared__ float s1[32][32];
    __shared__ float s2[32][32];
    __shared__ float xs[32][32];
    __shared__ float t1[32][64];
    __shared__ float wd[32][32], wsg[32][32];
    __shared__ float hc[32][64];
    __shared__ float mu[64], ivr[64];
    const int tid = threadIdx.x;

    for (int i = tid; i < 512; i += 256) {
        const int nn = i >> 4, k = i & 15;
        ss[nn][k] = input[((size_t)(nn * T_ + (T_ - 1)) * B_ + basin_idx[nn]) * 48 + 32 + k];
    }
    for (int i = tid; i < 1024; i += 256) xs[i >> 5][i & 31] = h_last[i];
    __syncthreads();

    // s1 = gelu(ss @ ps_W + ps_b)
    for (int i = tid; i < 1024; i += 256) {
        const int nn = i >> 5, p = i & 31;
        float a = ps_b[p];
        for (int k = 0; k < 16; ++k) a += ss[nn][k] * ps_W[k * 32 + p];
        s1[nn][p] = gelu_f(a);
    }
    __syncthreads();
    // s2 = gelu(s1 @ sp_W1 + sp_b1)
    for (int i = tid; i < 1024; i += 256) {
        const int nn = i >> 5, p = i & 31;
        float a = sp_b1[p];
        for (int k = 0; k < 32; ++k) a += s1[nn][k] * sp_W1[k * 32 + p];
        s2[nn][p] = gelu_f(a);
    }
    __syncthreads();
    // s3 = gelu(s2 @ sp_W2 + sp_b2) -> back into s1
    for (int i = tid; i < 1024; i += 256) {
        const int nn = i >> 5, p = i & 31;
        float a = sp_b2[p];
        for (int k = 0; k < 32; ++k) a += s2[nn][k] * sp_W2[k * 32 + p];
        s1[nn][p] = gelu_f(a);
    }
    __syncthreads();

    // t1 = gelu(xs @ gd_W1 + gd_b1)
    for (int i = tid; i < 2048; i += 256) {
        const int nn = i >> 6, e = i & 63;
        float a = gd_b1[e];
        for (int k = 0; k < 32; ++k) a += xs[nn][k] * gd_W1[k * 64 + e];
        t1[nn][e] = gelu_f(a);
    }
    __syncthreads();
    // wd = sigmoid(t1 @ gd_W2 + gd_b2)
    for (int i = tid; i < 1024; i += 256) {
        const int nn = i >> 5, p = i & 31;
        float a = gd_b2[p];
        for (int k = 0; k < 64; ++k) a += t1[nn][k] * gd_W2[k * 32 + p];
        wd[nn][p] = sigmoid_f(a);
    }
    __syncthreads();
    // t1 = gelu(xs @ gs_W1 + gs_b1)
    for (int i = tid; i < 2048; i += 256) {
        const int nn = i >> 6, e = i & 63;
        float a = gs_b1[e];
        for (int k = 0; k < 32; ++k) a += xs[nn][k] * gs_W1[k * 64 + e];
        t1[nn][e] = gelu_f(a);
    }
    __syncthreads();
    // wsg = sigmoid(t1 @ gs_W2 + gs_b2)
    for (int i = tid; i < 1024; i += 256) {
        const int nn = i >> 5, p = i & 31;
        float a = gs_b2[p];
        for (int k = 0; k < 64; ++k) a += t1[nn][k] * gs_W2[k * 32 + p];
        wsg[nn][p] = sigmoid_f(a);
    }
    __syncthreads();

    // hcat
    for (int i = tid; i < 2048; i += 256) {
        const int nn = i >> 6, cc = i & 63;
        hc[nn][cc] = (cc < 32) ? xs[nn][cc] * wd[nn][cc]
                               : s1[nn][cc - 32] * wsg[nn][cc - 32];
    }
    __syncthreads();

    // batchnorm stats over the 32 rows (biased var, two-pass like reference)
    if (tid < 64) {
        float m = 0.f;
        for (int nn = 0; nn < 32; ++nn) m += hc[nn][tid];
        m *= (1.0f / 32.0f);
        float v = 0.f;
        for (int nn = 0; nn < 32; ++nn) { const float d = hc[nn][tid] - m; v += d * d; }
        v *= (1.0f / 32.0f);
        mu[tid] = m;
        ivr[tid] = 1.0f / sqrtf(v + 1e-5f);
    }
    __syncthreads();

    if (tid < 32) {
        float a = r_b[0];
        for (int cc = 0; cc < 64; ++cc) {
            const float hn = (hc[tid][cc] - mu[cc]) * ivr[cc] * bn_g[cc] + bn_b[cc];
            a += hn * r_W[cc];
        }
        out[tid] = a;
    }
}

// ---------------- launcher ----------------
extern "C" void kernel_launch(void* const* d_in, const int* in_sizes, int n_in,
                              void* d_out, int out_size, void* d_ws, size_t ws_size,
                              hipStream_t stream) {
    const float* input  = (const float*)d_in[0];
    const float* adj    = (const float*)d_in[1];
    const int*   basin  = (const int*)  d_in[2];
    const float* pd_W   = (const float*)d_in[3];
    const float* pd_b   = (const float*)d_in[4];
    const float* ps_W   = (const float*)d_in[5];
    const float* ps_b   = (const float*)d_in[6];
    const float* g1_W   = (const float*)d_in[7];
    const float* g1_b   = (const float*)d_in[8];
    const float* g2_W   = (const float*)d_in[9];
    const float* g2_b   = (const float*)d_in[10];
    const float* l_Wih  = (const float*)d_in[11];
    const float* l_Whh  = (const float*)d_in[12];
    const float* l_bih  = (const float*)d_in[13];
    const float* l_bhh  = (const float*)d_in[14];
    const float* gd_W1  = (const float*)d_in[15];
    const float* gd_b1  = (const float*)d_in[16];
    const float* gd_W2  = (const float*)d_in[17];
    const float* gd_b2  = (const float*)d_in[18];
    const float* gs_W1  = (const float*)d_in[19];
    const float* gs_b1  = (const float*)d_in[20];
    const float* gs_W2  = (const float*)d_in[21];
    const float* gs_b2  = (const float*)d_in[22];
    const float* sp_W1  = (const float*)d_in[23];
    const float* sp_b1  = (const float*)d_in[24];
    const float* sp_W2  = (const float*)d_in[25];
    const float* sp_b2  = (const float*)d_in[26];
    const float* bn_g   = (const float*)d_in[27];
    const float* bn_b   = (const float*)d_in[28];
    const float* r_W    = (const float*)d_in[29];
    const float* r_b    = (const float*)d_in[30];
    float* out = (float*)d_out;

    float* ws       = (float*)d_ws;
    float* adjn_rm  = ws;                                // 16384 floats
    float* adjnT    = ws + 16384;                        // 16384 floats
    float* xg       = ws + 32768;                        // N*T*128 = 1,495,040 floats
    float* h_last   = xg + (size_t)N_ * T_ * 128;        // 1024 floats

    hipLaunchKernelGGL(prep_adj, dim3(1), dim3(128), 0, stream, adj, adjn_rm, adjnT);
    hipLaunchKernelGGL(gcn_fused, dim3(N_ * T_), dim3(256), 0, stream,
                       input, adjn_rm, adjnT, basin,
                       pd_W, pd_b, g1_W, g1_b, g2_W, g2_b,
                       l_Wih, l_bih, l_bhh, xg);
    hipLaunchKernelGGL(lstm_k, dim3(N_), dim3(64), 0, stream, xg, l_Whh, h_last);
    hipLaunchKernelGGL(final_k, dim3(1), dim3(256), 0, stream,
                       input, basin, h_last,
                       ps_W, ps_b, sp_W1, sp_b1, sp_W2, sp_b2,
                       gd_W1, gd_b1, gd_W2, gd_b2,
                       gs_W1, gs_b1, gs_W2, gs_b2,
                       bn_g, bn_b, r_W, r_b, out);
}